// Round 6
// baseline (139.756 us; speedup 1.0000x reference)
//
#include <hip/hip_runtime.h>
#include <math.h>

#define EPSF 1e-8f

typedef __attribute__((ext_vector_type(4))) short short4v;
typedef __attribute__((ext_vector_type(8))) short short8v;
typedef __attribute__((ext_vector_type(4))) float float4v;

__device__ inline short f2bf(float f) {
    unsigned u = __builtin_bit_cast(unsigned, f);
    unsigned r = (u + 0x7FFFu + ((u >> 16) & 1u)) >> 16;
    return (short)r;
}
__device__ inline float bf2f(short s) {
    unsigned u = ((unsigned)(unsigned short)s) << 16;
    return __builtin_bit_cast(float, u);
}

// F layout (bf16 shorts): f1t @0 (4*128*4096), f1s @2097152, f2t @4194304
// (4*256*1024), f2s @5242880; total 6291456 shorts = 12.6 MB.
#define F1T 0
#define F1S 2097152
#define F2T 4194304
#define F2S 5242880

// Gram trick: ||S1-S2||_F^2 = ||AA^T||^2 - 2||AB^T||^2 + ||BB^T||^2 over c x c
// grams (k = hw). 128x128 tiles: full-matrix sums (both triangles counted
// naturally). g1 (c=128): whole gram = one tile; 3 jobs/b {tt w1, ss w1,
// ts w-2}. g2 (c=256): 2x2 grid of 128-tiles; symmetric grams use upper
// triangle w={1,2,1}, cross all 4 quads w=-2 -> 10 jobs/b (table below).
__constant__ int g2q_tab[10][4] = {     // {type, qi, qj, w}
    {0,0,0,1},{0,0,1,2},{0,1,1,1},
    {1,0,0,1},{1,0,1,2},{1,1,1,1},
    {2,0,0,-2},{2,0,1,-2},{2,1,0,-2},{2,1,1,-2},
};

// ------------- prep: single-pass norm + normalize + bf16 convert -----------
// 1280 blocks x 32 px. 8 px-groups x 32 channel-slices. Raw values stashed
// in registers as packed bf16; inputs read ONCE. (verified rounds 0-5)
template<int C, int HW>
__device__ inline void prep_body(const float* __restrict__ x,
                                 short* __restrict__ f, int lp, int t)
{
    const int lanei = t & 7, slice = t >> 3;     // 8 groups x 32 slices
    const int b = lp / HW, m = lp - b * HW;
    const float* p = x + (size_t)b * C * HW + m;
    short*       q = f + (size_t)b * C * HW + m;
    constexpr int CPR = C >> 5;          // rows per slice (4 or 8)
    short4v vals[CPR];
    float4 s0 = {0.f,0.f,0.f,0.f}, s1 = {0.f,0.f,0.f,0.f};
#pragma unroll
    for (int i = 0; i < CPR; i += 2) {
        float4 v0 = *(const float4*)(p + (size_t)(slice * CPR + i)     * HW);
        float4 v1 = *(const float4*)(p + (size_t)(slice * CPR + i + 1) * HW);
        s0.x += v0.x * v0.x; s0.y += v0.y * v0.y;
        s0.z += v0.z * v0.z; s0.w += v0.w * v0.w;
        s1.x += v1.x * v1.x; s1.y += v1.y * v1.y;
        s1.z += v1.z * v1.z; s1.w += v1.w * v1.w;
        vals[i]     = (short4v){ f2bf(v0.x), f2bf(v0.y), f2bf(v0.z), f2bf(v0.w) };
        vals[i + 1] = (short4v){ f2bf(v1.x), f2bf(v1.y), f2bf(v1.z), f2bf(v1.w) };
    }
    float4 s = { s0.x + s1.x, s0.y + s1.y, s0.z + s1.z, s0.w + s1.w };
    __shared__ float4 red[32][8];
    __shared__ float4 invl[8];
    red[slice][lanei] = s;
    __syncthreads();
    if (t < 8) {
        float4 tot = {0.f,0.f,0.f,0.f};
#pragma unroll
        for (int sl = 0; sl < 32; ++sl) {
            float4 v = red[sl][t];
            tot.x += v.x; tot.y += v.y; tot.z += v.z; tot.w += v.w;
        }
        invl[t] = (float4){ 1.f / (sqrtf(tot.x) + EPSF), 1.f / (sqrtf(tot.y) + EPSF),
                            1.f / (sqrtf(tot.z) + EPSF), 1.f / (sqrtf(tot.w) + EPSF) };
    }
    __syncthreads();
    const float4 iv = invl[lanei];
#pragma unroll
    for (int i = 0; i < CPR; ++i) {
        const int r = slice * CPR + i;
        short4v rv = vals[i];
        short4v o = { f2bf(bf2f(rv[0]) * iv.x), f2bf(bf2f(rv[1]) * iv.y),
                      f2bf(bf2f(rv[2]) * iv.z), f2bf(bf2f(rv[3]) * iv.w) };
        *(short4v*)(q + (size_t)r * HW) = o;
    }
}

__global__ __launch_bounds__(256) void prep_kernel(
    const float* __restrict__ x1t, const float* __restrict__ x1s,
    const float* __restrict__ x2t, const float* __restrict__ x2s,
    short* __restrict__ F, float* __restrict__ out,
    unsigned* __restrict__ cnt)
{
    const int gp = blockIdx.x * 32;
    const int t = threadIdx.x;
    const int lanei = t & 7;
    if (blockIdx.x == 0 && t < 4) out[t] = 0.f;        // replaces memset
    if (blockIdx.x == 0 && t >= 8 && t < 61) cnt[t - 8] = 0u; // 52 tiles + gcnt
    if (gp < 16384)
        prep_body<128, 4096>(x1t, F + F1T, gp + lanei * 4, t);
    else if (gp < 32768)
        prep_body<128, 4096>(x1s, F + F1S, gp - 16384 + lanei * 4, t);
    else if (gp < 36864)
        prep_body<256, 1024>(x2t, F + F2T, gp - 32768 + lanei * 4, t);
    else
        prep_body<256, 1024>(x2s, F + F2S, gp - 36864 + lanei * 4, t);
}

// ------------- gram tile body: 128x128, LDS-staged, BK=64, 8 stages -------
// Stage [128][64] tiles (A, and B unless SHARE) via coalesced 16B/lane
// loads with T14 prefetch (next stage's loads issue before compute). LDS
// row stride 72 shorts (144B = 36 dw, stride mod 32 = 4 -> same bank
// pattern as the verified LSTR-136 kernel). 4 waves in 2x2, each 64x64
// (4x4 frags). acc complete over the 512-k chunk.
#define ASTR 72

template<int HW, bool SHARE>
__device__ inline void gram_tile128(const short* __restrict__ Fa,
                                    const short* __restrict__ Fb,
                                    int k0, int t,
                                    short* __restrict__ ldsA,
                                    short* __restrict__ ldsB,
                                    float4v (&acc)[4][4])
{
    const int lane = t & 63, w = t >> 6;
    const int r16 = lane & 15, quad = lane >> 4;
    const int wr = w >> 1, wc = w & 1;
    const int srow = t >> 3, skc = (t & 7) * 8;   // stage: 32 rows x 8 kcols

    short8v ar[4], br[4];
#pragma unroll
    for (int p = 0; p < 4; ++p)
        ar[p] = *(const short8v*)(Fa + (size_t)(p * 32 + srow) * HW + k0 + skc);
    if (!SHARE) {
#pragma unroll
        for (int p = 0; p < 4; ++p)
            br[p] = *(const short8v*)(Fb + (size_t)(p * 32 + srow) * HW + k0 + skc);
    }

#pragma unroll 1
    for (int st = 0; st < 8; ++st) {
#pragma unroll
        for (int p = 0; p < 4; ++p)
            *(short8v*)(ldsA + (p * 32 + srow) * ASTR + skc) = ar[p];
        if (!SHARE) {
#pragma unroll
            for (int p = 0; p < 4; ++p)
                *(short8v*)(ldsB + (p * 32 + srow) * ASTR + skc) = br[p];
        }
        __syncthreads();
        if (st < 7) {                    // T14: issue next-stage loads early
            const int k1 = k0 + (st + 1) * 64;
#pragma unroll
            for (int p = 0; p < 4; ++p)
                ar[p] = *(const short8v*)(Fa + (size_t)(p * 32 + srow) * HW + k1 + skc);
            if (!SHARE) {
#pragma unroll
                for (int p = 0; p < 4; ++p)
                    br[p] = *(const short8v*)(Fb + (size_t)(p * 32 + srow) * HW + k1 + skc);
            }
        }
        const short* A = ldsA;
        const short* B = SHARE ? ldsA : ldsB;
#pragma unroll
        for (int ks = 0; ks < 2; ++ks) {
            short8v af[4], bf[4];
#pragma unroll
            for (int i = 0; i < 4; ++i)
                af[i] = *(const short8v*)(A + (wr * 64 + i * 16 + r16) * ASTR + ks * 32 + quad * 8);
#pragma unroll
            for (int j = 0; j < 4; ++j)
                bf[j] = *(const short8v*)(B + (wc * 64 + j * 16 + r16) * ASTR + ks * 32 + quad * 8);
#pragma unroll
            for (int i = 0; i < 4; ++i)
#pragma unroll
                for (int j = 0; j < 4; ++j)
                    acc[i][j] = __builtin_amdgcn_mfma_f32_16x16x32_bf16(
                        af[i], bf[j], acc[i][j], 0, 0, 0);
        }
        __syncthreads();
    }
}

// ------------- gram kernel: 176 blocks x 256 thr; merged finalize ----------
// g1 (id<96): job = id/8 (type*4+b), ks = id%8 -> 512-k chunk of the full
// 128x128 gram; P=8 partials/tile, 12 tiles. g2: id2=id-96, job=id2/2,
// ks=id2%1? no: ks=id2&1; 40 tiles, P=2. Last block per tile (rocPRIM
// counter pattern) sums P slabs, squares, weights, one atomicAdd(out[which]);
// global counter finalizes out[0..1] (r5-verified protocol).
__global__ __launch_bounds__(256, 2) void gram_kernel(
    const short* __restrict__ F, float* __restrict__ partials,
    float* __restrict__ out, unsigned* __restrict__ cnt)
{
    __shared__ __align__(16) short ldsA[128 * ASTR];
    __shared__ __align__(16) short ldsB[128 * ASTR];
    __shared__ float sc[4];
    __shared__ int fin;

    const int id = blockIdx.x;
    const int t = threadIdx.x, w = t >> 6, lane = t & 63;
    const int r16 = lane & 15, quad = lane >> 4;
    const int wr = w >> 1, wc = w & 1;

    float4v acc[4][4];
#pragma unroll
    for (int i = 0; i < 4; ++i)
#pragma unroll
        for (int j = 0; j < 4; ++j) acc[i][j] = (float4v){0.f, 0.f, 0.f, 0.f};

    int tile, P, slab, slab0, which;
    float wt;
    if (id < 96) {                       // group 1: c=128, k=4096
        const int jb = id >> 3, ks = id & 7;
        const int type = jb >> 2, b = jb & 3;
        const int k0 = ks * 512;
        const short* Fa = (type == 1 ? F + F1S : F + F1T) + (size_t)b * 524288;
        const short* Fb = (type == 0 ? F + F1T : F + F1S) + (size_t)b * 524288;
        if (type < 2) gram_tile128<4096, true >(Fa, Fa, k0, t, ldsA, ldsB, acc);
        else          gram_tile128<4096, false>(Fa, Fb, k0, t, ldsA, ldsB, acc);
        tile = jb; P = 8; slab0 = jb * 8; slab = slab0 + ks;
        wt = (type == 2 ? -2.f : 1.f) * (1.0f / (4096.f * 4096.f * 4.f));
        which = 2;
    } else {                             // group 2: c=256, k=1024
        const int id2 = id - 96;
        const int job = id2 >> 1, ks = id2 & 1;
        const int b = job / 10, j10 = job - b * 10;
        const int type = g2q_tab[j10][0];
        const int qi = g2q_tab[j10][1], qj = g2q_tab[j10][2];
        const int k0 = ks * 512;
        const short* Fa = (type == 1 ? F + F2S : F + F2T)
                          + (size_t)(b * 256 + qi * 128) * 1024;
        const short* Fb = (type == 0 ? F + F2T : F + F2S)
                          + (size_t)(b * 256 + qj * 128) * 1024;
        if (type < 2 && qi == qj)
            gram_tile128<1024, true >(Fa, Fa, k0, t, ldsA, ldsB, acc);
        else
            gram_tile128<1024, false>(Fa, Fb, k0, t, ldsA, ldsB, acc);
        tile = 12 + job; P = 2; slab0 = 96 + job * 2; slab = slab0 + ks;
        wt = (float)g2q_tab[j10][3] * (1.0f / (1024.f * 1024.f * 4.f));
        which = 3;
    }

    // ---- write 128x128 fp32 k-partial slab (wave-owned strips) ------------
    // C/D layout: col = lane&15, row = quad*4 + reg.
    float* dst = partials + (size_t)slab * 16384;
#pragma unroll
    for (int i = 0; i < 4; ++i)
#pragma unroll
        for (int j = 0; j < 4; ++j)
#pragma unroll
            for (int r = 0; r < 4; ++r)
                dst[(wr * 64 + i * 16 + quad * 4 + r) * 128 + wc * 64 + j * 16 + r16]
                    = acc[i][j][r];

    // ---- last-block-per-tile finalize (rocPRIM pattern) -------------------
    __syncthreads();
    if (t == 0) {
        __threadfence();                 // release partial slab
        unsigned old = atomicAdd(&cnt[tile], 1u);
        fin = (old == (unsigned)(P - 1)) ? 1 : 0;
    }
    __syncthreads();
    if (fin) {
        __threadfence();                 // acquire: see all P slabs
        const float* base = partials + (size_t)slab0 * 16384;
        float s = 0.f;
#pragma unroll 1
        for (int c = 0; c < 16; ++c) {
            const int idx = (c * 256 + t) * 4;   // lane-consecutive float4
            float4 v = {0.f, 0.f, 0.f, 0.f};
            for (int p = 0; p < P; ++p) {
                float4 u = *(const float4*)(base + (size_t)p * 16384 + idx);
                v.x += u.x; v.y += u.y; v.z += u.z; v.w += u.w;
            }
            s += v.x * v.x + v.y * v.y + v.z * v.z + v.w * v.w;
        }
        s *= wt;
#pragma unroll
        for (int o = 32; o > 0; o >>= 1) s += __shfl_down(s, o);
        if (lane == 0) sc[w] = s;
        __syncthreads();
        if (t == 0) {
            float val = sc[0] + sc[1] + sc[2] + sc[3];
            atomicAdd(&out[which], val); // stack[1]=pwl_g1 / stack[2]=pwl_g2
            __threadfence();             // add visible before counter bump
            unsigned gold = atomicAdd(&cnt[52], 1u);
            if (gold == 51u) {           // all 52 tiles done: finalize loss
                float g1v = __hip_atomic_load(&out[2], __ATOMIC_RELAXED,
                                              __HIP_MEMORY_SCOPE_AGENT);
                float g2v = __hip_atomic_load(&out[3], __ATOMIC_RELAXED,
                                              __HIP_MEMORY_SCOPE_AGENT);
                float loss = g1v + g2v;
                out[0] = loss;           // loss
                out[1] = loss;           // stack[0] = loss
            }
        }
    }
}

extern "C" void kernel_launch(void* const* d_in, const int* in_sizes, int n_in,
                              void* d_out, int out_size, void* d_ws, size_t ws_size,
                              hipStream_t stream)
{
    const float* x1t = (const float*)d_in[0];   // [4,128,64,64]
    const float* x1s = (const float*)d_in[1];
    const float* x2t = (const float*)d_in[2];   // [4,256,32,32]
    const float* x2s = (const float*)d_in[3];

    short* F         = (short*)d_ws;             // 6291456 shorts (12.6 MB)
    float* partials  = (float*)d_ws + 3200000;   // 176 x 16384 floats (11.5 MB)
    unsigned* cnt    = (unsigned*)((float*)d_ws + 6200000); // 52 tiles + gcnt

    prep_kernel<<<1280, 256, 0, stream>>>(x1t, x1s, x2t, x2s, F,
                                          (float*)d_out, cnt);
    gram_kernel<<<176, 256, 0, stream>>>(F, partials, (float*)d_out, cnt);
}

// Round 8
// 94.577 us; speedup vs baseline: 1.4777x; 1.4777x over previous
//
#include <hip/hip_runtime.h>
#include <math.h>

#define EPSF 1e-8f

typedef __attribute__((ext_vector_type(4))) short short4v;
typedef __attribute__((ext_vector_type(8))) short short8v;
typedef __attribute__((ext_vector_type(4))) float float4v;

__device__ inline short f2bf(float f) {
    unsigned u = __builtin_bit_cast(unsigned, f);
    unsigned r = (u + 0x7FFFu + ((u >> 16) & 1u)) >> 16;
    return (short)r;
}
__device__ inline float bf2f(short s) {
    unsigned u = ((unsigned)(unsigned short)s) << 16;
    return __builtin_bit_cast(float, u);
}

// F layout (bf16 shorts): f1t @0 (4*128*4096), f1s @2097152, f2t @4194304
// (4*256*1024), f2s @5242880; total 6291456 shorts = 12.6 MB.
#define F1T 0
#define F1S 2097152
#define F2T 4194304
#define F2S 5242880

// Gram trick: ||S1-S2||_F^2 = ||AA^T||^2 - 2||AB^T||^2 + ||BB^T||^2 over c x c
// grams (k = hw). 128x128 tiles (full-matrix sums). g1 (c=128): whole gram =
// one tile; 3 jobs/b {tt w1, ss w1, ts w-2}. g2 (c=256): 2x2 grid of
// 128-tiles; symmetric grams upper triangle w={1,2,1}, cross all 4 quads
// w=-2 -> 10 jobs/b. (geometry verified round 6, absmax=0)
__constant__ int g2q_tab[10][4] = {     // {type, qi, qj, w}
    {0,0,0,1},{0,0,1,2},{0,1,1,1},
    {1,0,0,1},{1,0,1,2},{1,1,1,1},
    {2,0,0,-2},{2,0,1,-2},{2,1,0,-2},{2,1,1,-2},
};

// ------------- prep: single-pass norm + normalize + bf16 convert -----------
// 1280 blocks x 32 px. 8 px-groups x 32 channel-slices. Raw values stashed
// in registers as packed bf16; inputs read ONCE. (verified rounds 0-6)
template<int C, int HW>
__device__ inline void prep_body(const float* __restrict__ x,
                                 short* __restrict__ f, int lp, int t)
{
    const int lanei = t & 7, slice = t >> 3;     // 8 groups x 32 slices
    const int b = lp / HW, m = lp - b * HW;
    const float* p = x + (size_t)b * C * HW + m;
    short*       q = f + (size_t)b * C * HW + m;
    constexpr int CPR = C >> 5;          // rows per slice (4 or 8)
    short4v vals[CPR];
    float4 s0 = {0.f,0.f,0.f,0.f}, s1 = {0.f,0.f,0.f,0.f};
#pragma unroll
    for (int i = 0; i < CPR; i += 2) {
        float4 v0 = *(const float4*)(p + (size_t)(slice * CPR + i)     * HW);
        float4 v1 = *(const float4*)(p + (size_t)(slice * CPR + i + 1) * HW);
        s0.x += v0.x * v0.x; s0.y += v0.y * v0.y;
        s0.z += v0.z * v0.z; s0.w += v0.w * v0.w;
        s1.x += v1.x * v1.x; s1.y += v1.y * v1.y;
        s1.z += v1.z * v1.z; s1.w += v1.w * v1.w;
        vals[i]     = (short4v){ f2bf(v0.x), f2bf(v0.y), f2bf(v0.z), f2bf(v0.w) };
        vals[i + 1] = (short4v){ f2bf(v1.x), f2bf(v1.y), f2bf(v1.z), f2bf(v1.w) };
    }
    float4 s = { s0.x + s1.x, s0.y + s1.y, s0.z + s1.z, s0.w + s1.w };
    __shared__ float4 red[32][8];
    __shared__ float4 invl[8];
    red[slice][lanei] = s;
    __syncthreads();
    if (t < 8) {
        float4 tot = {0.f,0.f,0.f,0.f};
#pragma unroll
        for (int sl = 0; sl < 32; ++sl) {
            float4 v = red[sl][t];
            tot.x += v.x; tot.y += v.y; tot.z += v.z; tot.w += v.w;
        }
        invl[t] = (float4){ 1.f / (sqrtf(tot.x) + EPSF), 1.f / (sqrtf(tot.y) + EPSF),
                            1.f / (sqrtf(tot.z) + EPSF), 1.f / (sqrtf(tot.w) + EPSF) };
    }
    __syncthreads();
    const float4 iv = invl[lanei];
#pragma unroll
    for (int i = 0; i < CPR; ++i) {
        const int r = slice * CPR + i;
        short4v rv = vals[i];
        short4v o = { f2bf(bf2f(rv[0]) * iv.x), f2bf(bf2f(rv[1]) * iv.y),
                      f2bf(bf2f(rv[2]) * iv.z), f2bf(bf2f(rv[3]) * iv.w) };
        *(short4v*)(q + (size_t)r * HW) = o;
    }
}

__global__ __launch_bounds__(256) void prep_kernel(
    const float* __restrict__ x1t, const float* __restrict__ x1s,
    const float* __restrict__ x2t, const float* __restrict__ x2s,
    short* __restrict__ F, float* __restrict__ out,
    unsigned* __restrict__ cnt)
{
    const int gp = blockIdx.x * 32;
    const int t = threadIdx.x;
    const int lanei = t & 7;
    if (blockIdx.x == 0 && t < 4) out[t] = 0.f;   // replaces memset dispatch
    if (blockIdx.x == 0 && t == 4) *cnt = 0u;     // finalize counter reset
    if (gp < 16384)
        prep_body<128, 4096>(x1t, F + F1T, gp + lanei * 4, t);
    else if (gp < 32768)
        prep_body<128, 4096>(x1s, F + F1S, gp - 16384 + lanei * 4, t);
    else if (gp < 36864)
        prep_body<256, 1024>(x2t, F + F2T, gp - 32768 + lanei * 4, t);
    else
        prep_body<256, 1024>(x2s, F + F2S, gp - 36864 + lanei * 4, t);
}

// ------------- gram tile body: 128x128, LDS-staged, BK=64, 8 stages -------
// Stage [128][64] tiles (A, and B unless SHARE) via coalesced 16B/lane
// loads with T14 prefetch. LDS row stride 72 shorts (144B). 4 waves in
// 2x2, each 64x64 (4x4 frags). acc complete over the 512-k chunk.
// (verified round 6, absmax=0)
#define ASTR 72

template<int HW, bool SHARE>
__device__ inline void gram_tile128(const short* __restrict__ Fa,
                                    const short* __restrict__ Fb,
                                    int k0, int t,
                                    short* __restrict__ ldsA,
                                    short* __restrict__ ldsB,
                                    float4v (&acc)[4][4])
{
    const int lane = t & 63, w = t >> 6;
    const int r16 = lane & 15, quad = lane >> 4;
    const int wr = w >> 1, wc = w & 1;
    const int srow = t >> 3, skc = (t & 7) * 8;   // stage: 32 rows x 8 kcols

    short8v ar[4], br[4];
#pragma unroll
    for (int p = 0; p < 4; ++p)
        ar[p] = *(const short8v*)(Fa + (size_t)(p * 32 + srow) * HW + k0 + skc);
    if (!SHARE) {
#pragma unroll
        for (int p = 0; p < 4; ++p)
            br[p] = *(const short8v*)(Fb + (size_t)(p * 32 + srow) * HW + k0 + skc);
    }

#pragma unroll 1
    for (int st = 0; st < 8; ++st) {
#pragma unroll
        for (int p = 0; p < 4; ++p)
            *(short8v*)(ldsA + (p * 32 + srow) * ASTR + skc) = ar[p];
        if (!SHARE) {
#pragma unroll
            for (int p = 0; p < 4; ++p)
                *(short8v*)(ldsB + (p * 32 + srow) * ASTR + skc) = br[p];
        }
        __syncthreads();
        if (st < 7) {                    // T14: issue next-stage loads early
            const int k1 = k0 + (st + 1) * 64;
#pragma unroll
            for (int p = 0; p < 4; ++p)
                ar[p] = *(const short8v*)(Fa + (size_t)(p * 32 + srow) * HW + k1 + skc);
            if (!SHARE) {
#pragma unroll
                for (int p = 0; p < 4; ++p)
                    br[p] = *(const short8v*)(Fb + (size_t)(p * 32 + srow) * HW + k1 + skc);
            }
        }
        const short* A = ldsA;
        const short* B = SHARE ? ldsA : ldsB;
#pragma unroll
        for (int ks = 0; ks < 2; ++ks) {
            short8v af[4], bf[4];
#pragma unroll
            for (int i = 0; i < 4; ++i)
                af[i] = *(const short8v*)(A + (wr * 64 + i * 16 + r16) * ASTR + ks * 32 + quad * 8);
#pragma unroll
            for (int j = 0; j < 4; ++j)
                bf[j] = *(const short8v*)(B + (wc * 64 + j * 16 + r16) * ASTR + ks * 32 + quad * 8);
#pragma unroll
            for (int i = 0; i < 4; ++i)
#pragma unroll
                for (int j = 0; j < 4; ++j)
                    acc[i][j] = __builtin_amdgcn_mfma_f32_16x16x32_bf16(
                        af[i], bf[j], acc[i][j], 0, 0, 0);
        }
        __syncthreads();
    }
}

// ------------- gram kernel: 176 blocks x 256 thr; slab writes only --------
// g1 (id<96): jb=id/8 (type*4+b), ks=id%8 -> slab jb*8+ks. g2: id2=id-96,
// job=id2/2, ks=id2&1 -> slab 96+job*2+ks. Finalize moved to fin_kernel
// (round-6 post-mortem: in-kernel last-block finalize with runtime-P loop
// serialized ~128 dependent-latency loads on 52 near-solo blocks = 60us tail).
__global__ __launch_bounds__(256, 2) void gram_kernel(
    const short* __restrict__ F, float* __restrict__ partials)
{
    __shared__ __align__(16) short ldsA[128 * ASTR];
    __shared__ __align__(16) short ldsB[128 * ASTR];

    const int id = blockIdx.x;
    const int t = threadIdx.x, w = t >> 6, lane = t & 63;
    const int r16 = lane & 15, quad = lane >> 4;
    const int wr = w >> 1, wc = w & 1;

    float4v acc[4][4];
#pragma unroll
    for (int i = 0; i < 4; ++i)
#pragma unroll
        for (int j = 0; j < 4; ++j) acc[i][j] = (float4v){0.f, 0.f, 0.f, 0.f};

    int slab;
    if (id < 96) {                       // group 1: c=128, k=4096
        const int jb = id >> 3, ks = id & 7;
        const int type = jb >> 2, b = jb & 3;
        const int k0 = ks * 512;
        const short* Fa = (type == 1 ? F + F1S : F + F1T) + (size_t)b * 524288;
        const short* Fb = (type == 0 ? F + F1T : F + F1S) + (size_t)b * 524288;
        if (type < 2) gram_tile128<4096, true >(Fa, Fa, k0, t, ldsA, ldsB, acc);
        else          gram_tile128<4096, false>(Fa, Fb, k0, t, ldsA, ldsB, acc);
        slab = jb * 8 + ks;
    } else {                             // group 2: c=256, k=1024
        const int id2 = id - 96;
        const int job = id2 >> 1, ks = id2 & 1;
        const int b = job / 10, j10 = job - b * 10;
        const int type = g2q_tab[j10][0];
        const int qi = g2q_tab[j10][1], qj = g2q_tab[j10][2];
        const int k0 = ks * 512;
        const short* Fa = (type == 1 ? F + F2S : F + F2T)
                          + (size_t)(b * 256 + qi * 128) * 1024;
        const short* Fb = (type == 0 ? F + F2T : F + F2S)
                          + (size_t)(b * 256 + qj * 128) * 1024;
        if (type < 2 && qi == qj)
            gram_tile128<1024, true >(Fa, Fa, k0, t, ldsA, ldsB, acc);
        else
            gram_tile128<1024, false>(Fa, Fb, k0, t, ldsA, ldsB, acc);
        slab = 96 + job * 2 + ks;
    }

    // ---- write 128x128 fp32 k-partial slab (wave-owned strips) ------------
    // C/D layout: col = lane&15, row = quad*4 + reg.
    float* dst = partials + (size_t)slab * 16384;
#pragma unroll
    for (int i = 0; i < 4; ++i)
#pragma unroll
        for (int j = 0; j < 4; ++j)
#pragma unroll
            for (int r = 0; r < 4; ++r)
                dst[(wr * 64 + i * 16 + quad * 4 + r) * 128 + wc * 64 + j * 16 + r16]
                    = acc[i][j][r];
}

// ------------- finalize: 208 blocks (4/tile); unrolled P, r5 protocol ------
// Per thread: 4 coalesced float4s x P independent loads (32 or 8 in flight,
// compile-time unrolled). One atomicAdd(out[which]) per block; global
// counter last-block writes out[0..1]. (protocol verified round 5)
template<int P>
__device__ inline float fin_sum(const float* __restrict__ base, int part, int t)
{
    float s = 0.f;
    const int off = part * 4096 + t * 4;
#pragma unroll
    for (int i = 0; i < 4; ++i) {
        const int idx = off + i * 1024;
        float4 v = {0.f, 0.f, 0.f, 0.f};
#pragma unroll
        for (int p = 0; p < P; ++p) {
            float4 u = *(const float4*)(base + (size_t)p * 16384 + idx);
            v.x += u.x; v.y += u.y; v.z += u.z; v.w += u.w;
        }
        s += v.x * v.x + v.y * v.y + v.z * v.z + v.w * v.w;
    }
    return s;
}

__global__ __launch_bounds__(256) void fin_kernel(
    const float* __restrict__ partials, float* __restrict__ out,
    unsigned* __restrict__ cnt)
{
    __shared__ float sc[4];
    const int bid = blockIdx.x;
    const int t = threadIdx.x, lane = t & 63, w = t >> 6;

    float s, wt; int which;
    if (bid < 48) {                      // g1: 12 tiles x 4 parts, P=8
        const int tile = bid >> 2, part = bid & 3;
        const int type = tile >> 2;
        s = fin_sum<8>(partials + (size_t)tile * 8 * 16384, part, t);
        wt = (type == 2 ? -2.f : 1.f) * (1.0f / (4096.f * 4096.f * 4.f));
        which = 2;
    } else {                             // g2: 40 tiles x 4 parts, P=2
        const int b2 = bid - 48;
        const int job = b2 >> 2, part = b2 & 3;
        const int j10 = job % 10;
        s = fin_sum<2>(partials + (size_t)(96 + job * 2) * 16384, part, t);
        wt = (float)g2q_tab[j10][3] * (1.0f / (1024.f * 1024.f * 4.f));
        which = 3;
    }
    s *= wt;

#pragma unroll
    for (int o = 32; o > 0; o >>= 1) s += __shfl_down(s, o);
    if (lane == 0) sc[w] = s;
    __syncthreads();
    if (t == 0) {
        float val = sc[0] + sc[1] + sc[2] + sc[3];
        atomicAdd(&out[which], val);     // stack[1]=pwl_g1 / stack[2]=pwl_g2
        __threadfence();                 // add visible before counter bump
        unsigned old = atomicAdd(cnt, 1u);
        if (old == 207u) {               // last block: finalize loss
            float g1v = __hip_atomic_load(&out[2], __ATOMIC_RELAXED,
                                          __HIP_MEMORY_SCOPE_AGENT);
            float g2v = __hip_atomic_load(&out[3], __ATOMIC_RELAXED,
                                          __HIP_MEMORY_SCOPE_AGENT);
            float loss = g1v + g2v;
            out[0] = loss;               // loss
            out[1] = loss;               // stack[0] = loss
        }
    }
}

extern "C" void kernel_launch(void* const* d_in, const int* in_sizes, int n_in,
                              void* d_out, int out_size, void* d_ws, size_t ws_size,
                              hipStream_t stream)
{
    const float* x1t = (const float*)d_in[0];   // [4,128,64,64]
    const float* x1s = (const float*)d_in[1];
    const float* x2t = (const float*)d_in[2];   // [4,256,32,32]
    const float* x2s = (const float*)d_in[3];

    short* F        = (short*)d_ws;              // 6291456 shorts (12.6 MB)
    float* partials = (float*)d_ws + 3200000;    // 176 x 16384 floats (11.5 MB)
    unsigned* cnt   = (unsigned*)((float*)d_ws + 6200000);

    prep_kernel<<<1280, 256, 0, stream>>>(x1t, x1s, x2t, x2s, F,
                                          (float*)d_out, cnt);
    gram_kernel<<<176, 256, 0, stream>>>(F, partials);
    fin_kernel<<<208, 256, 0, stream>>>(partials, (float*)d_out, cnt);
}